// Round 1
// baseline (118.683 us; speedup 1.0000x reference)
//
#include <hip/hip_runtime.h>

#define LGL 16   // L channels
#define LGD 4    // ref dims

// Kernel 1: each thread owns one output row i, accumulates over a j-chunk.
// gridDim.x = n/256 (i tiles), gridDim.y = C (j chunks).
// out layout: [C][n][L] partials (or [n][L] directly when C==1).
__global__ __launch_bounds__(256) void lg_partial_kernel(
    const float* __restrict__ U, const float* __restrict__ ref,
    float* __restrict__ out, int n, int jlen) {
  const int i = blockIdx.x * blockDim.x + threadIdx.x;
  const int j0 = blockIdx.y * jlen;

  const float r0 = ref[i * LGD + 0];
  const float r1 = ref[i * LGD + 1];
  const float r2 = ref[i * LGD + 2];
  const float r3 = ref[i * LGD + 3];

  float acc[LGL];
#pragma unroll
  for (int l = 0; l < LGL; ++l) acc[l] = 0.0f;

  const float* __restrict__ refj = ref + (size_t)j0 * LGD;
  const float* __restrict__ Uj   = U   + (size_t)j0 * LGL;

#pragma unroll 2
  for (int j = 0; j < jlen; ++j) {
    // wave-uniform loads -> scalar broadcast
    const float d0 = r0 - refj[0];
    const float d1 = r1 - refj[1];
    const float d2c = r2 - refj[2];
    const float d3 = r3 - refj[3];
    const float dist2 = d0 * d0 + d1 * d1 + d2c * d2c + d3 * d3;
    const float w = __expf(-dist2);
#pragma unroll
    for (int l = 0; l < LGL; ++l) acc[l] += w * Uj[l];
    refj += LGD;
    Uj += LGL;
  }

  const size_t o = ((size_t)blockIdx.y * n + i) * LGL;
#pragma unroll
  for (int l = 0; l < LGL; ++l) out[o + l] = acc[l];
}

// Kernel 2: sum the C partials. Operates on float4 for coalescing.
__global__ __launch_bounds__(256) void lg_reduce_kernel(
    const float4* __restrict__ ws, float4* __restrict__ out, int t4, int C) {
  const int idx = blockIdx.x * blockDim.x + threadIdx.x;
  if (idx >= t4) return;
  float4 s = make_float4(0.f, 0.f, 0.f, 0.f);
  for (int c = 0; c < C; ++c) {
    const float4 v = ws[(size_t)c * t4 + idx];
    s.x += v.x; s.y += v.y; s.z += v.z; s.w += v.w;
  }
  out[idx] = s;
}

extern "C" void kernel_launch(void* const* d_in, const int* in_sizes, int n_in,
                              void* d_out, int out_size, void* d_ws, size_t ws_size,
                              hipStream_t stream) {
  const float* U   = (const float*)d_in[0];
  const float* ref = (const float*)d_in[1];
  float* out = (float*)d_out;

  const int n = in_sizes[1] / LGD;  // 8192
  const size_t per_chunk = (size_t)n * LGL * sizeof(float);

  // pick largest C (power of 2, <=32) whose partial buffer fits in d_ws
  int C = 32;
  while (C > 1 && (size_t)C * per_chunk > ws_size) C >>= 1;

  if (per_chunk <= ws_size) {
    float* ws = (float*)d_ws;
    const int jlen = n / C;
    dim3 grid(n / 256, C);
    lg_partial_kernel<<<grid, 256, 0, stream>>>(U, ref, ws, n, jlen);
    const int t4 = n * LGL / 4;
    lg_reduce_kernel<<<(t4 + 255) / 256, 256, 0, stream>>>(
        (const float4*)ws, (float4*)out, t4, C);
  } else {
    // workspace too small even for one partial: single chunk straight to out
    dim3 grid(n / 256, 1);
    lg_partial_kernel<<<grid, 256, 0, stream>>>(U, ref, out, n, n);
  }
}

// Round 2
// 78.751 us; speedup vs baseline: 1.5071x; 1.5071x over previous
//
#include <hip/hip_runtime.h>

#define LGL 16      // L channels
#define LGD 4       // ref dims
#define JT  512     // j-tile per block (K chunk)
#define RSCALE 1.2011224087f  // sqrt(log2(e)); (s*d)^2 sums to d2*log2(e)

typedef _Float16 f16x8 __attribute__((ext_vector_type(8)));
typedef float f32x4 __attribute__((ext_vector_type(4)));

// Grid: x = n/64 (i-tiles: 4 waves x 16 rows), y = n/JT (j-chunks).
// Each wave: 16 i-rows, sweeps JT j's in 32-j MFMA steps.
// W tile generated directly in A-fragment layout: lane(q,l) computes
// w(i0+l, j0+s*32+q*8+e) for e=0..7. U staged fp16 in B-fragment-major LDS.
__global__ __launch_bounds__(256) void lg_mfma_kernel(
    const float* __restrict__ U, const float* __restrict__ ref,
    float* __restrict__ out, int n) {
  __shared__ float sref[JT * LGD];        // scaled ref rows, 8 KB
  __shared__ _Float16 sU[JT * LGL];       // fragment-major fp16 U, 16 KB

  const int t = threadIdx.x;
  const int j0 = blockIdx.y * JT;

  // ---- stage ref (pre-scaled by sqrt(log2 e)) ----
  {
    const float4* g = (const float4*)ref + j0;  // one float4 per j row (d=4)
    float4* sr = (float4*)sref;
#pragma unroll
    for (int it = 0; it < JT / 256; ++it) {
      const int idx = t + it * 256;
      float4 v = g[idx];
      v.x *= RSCALE; v.y *= RSCALE; v.z *= RSCALE; v.w *= RSCALE;
      sr[idx] = v;
    }
  }
  // ---- stage U -> B-fragment-major fp16 ----
  // B-frag: lane(q,l) element e = U[j0 + s*32 + q*8 + e][l]
  // stored at half-index (s*64 + q*16 + l)*8 + e = s*512 + q*128 + l*8 + e
  {
    const float4* g = (const float4*)U + (size_t)j0 * (LGL / 4);
#pragma unroll
    for (int it = 0; it < JT * (LGL / 4) / 256; ++it) {
      const int idx = t + it * 256;     // float4 index: 4 per j row
      const int j_rel = idx >> 2;
      const int l0 = (idx & 3) << 2;
      const float4 v = g[idx];
      const int s = j_rel >> 5, q = (j_rel >> 3) & 3, e = j_rel & 7;
      const int base = s * 512 + q * 128 + e;
      sU[base + (l0 + 0) * 8] = (_Float16)v.x;
      sU[base + (l0 + 1) * 8] = (_Float16)v.y;
      sU[base + (l0 + 2) * 8] = (_Float16)v.z;
      sU[base + (l0 + 3) * 8] = (_Float16)v.w;
    }
  }
  __syncthreads();

  const int lane = t & 63;
  const int wv = t >> 6;
  const int l = lane & 15;
  const int q = lane >> 4;
  const int i0 = blockIdx.x * 64 + wv * 16;
  const int i = i0 + l;

  const float r0 = ref[i * LGD + 0] * RSCALE;
  const float r1 = ref[i * LGD + 1] * RSCALE;
  const float r2 = ref[i * LGD + 2] * RSCALE;
  const float r3 = ref[i * LGD + 3] * RSCALE;

  f32x4 acc = {0.f, 0.f, 0.f, 0.f};
  const float4* srj = (const float4*)sref;
  const f16x8* sb = (const f16x8*)sU;

  for (int s = 0; s < JT / 32; ++s) {
    f16x8 af;
    const int jb = s * 32 + q * 8;
#pragma unroll
    for (int e = 0; e < 8; ++e) {
      const float4 b = srj[jb + e];          // broadcast within quad
      const float d0 = r0 - b.x;
      const float d1 = r1 - b.y;
      const float d2 = r2 - b.z;
      const float d3 = r3 - b.w;
      const float dist = d0 * d0 + d1 * d1 + d2 * d2 + d3 * d3;
      af[e] = (_Float16)__builtin_amdgcn_exp2f(-dist);  // = exp(-||ri-rj||^2)
    }
    const f16x8 bf = sb[s * 64 + lane];      // lane-contiguous 16B, m97 pattern
    acc = __builtin_amdgcn_mfma_f32_16x16x32_f16(af, bf, acc, 0, 0, 0);
  }

  // C/D layout: col = lane&15 (=l), row = q*4 + reg (=i offset)
  float* o = out + ((size_t)(i0 + q * 4) * LGL) + l;
#pragma unroll
  for (int r = 0; r < 4; ++r) unsafeAtomicAdd(o + r * LGL, acc[r]);
}

extern "C" void kernel_launch(void* const* d_in, const int* in_sizes, int n_in,
                              void* d_out, int out_size, void* d_ws, size_t ws_size,
                              hipStream_t stream) {
  const float* U   = (const float*)d_in[0];
  const float* ref = (const float*)d_in[1];
  float* out = (float*)d_out;

  const int n = in_sizes[1] / LGD;  // 8192

  // out is re-poisoned before every timed call; atomics need zeros
  hipMemsetAsync(d_out, 0, (size_t)out_size * sizeof(float), stream);

  dim3 grid(n / 64, n / JT);
  lg_mfma_kernel<<<grid, 256, 0, stream>>>(U, ref, out, n);
}

// Round 3
// 72.622 us; speedup vs baseline: 1.6343x; 1.0844x over previous
//
#include <hip/hip_runtime.h>

#define LGL 16      // L channels
#define LGD 4       // ref dims
#define JT  256     // j-tile per block
#define RT  4       // i-tiles (16 rows each) per wave
#define RSCALE 1.2011224087f   // sqrt(log2 e)
#define SSTR4 257   // float4 stride of one skewed sref copy (JT + 1)

typedef _Float16 f16x8 __attribute__((ext_vector_type(8)));
typedef float f32x4 __attribute__((ext_vector_type(4)));

// out_i = sum_j exp2(2*(s ri)·(s rj) - |s ri|^2 - |s rj|^2) U_j , s^2 = log2 e
//       = sum_j exp(-||ri-rj||^2) U_j
// A-frag lane(q,l): a_e = exp2(rr_i · b_{j0+s*32+q*8+e} - ci), rr = s*ref_i,
// b = 2s*ref_j (pre-doubled in LDS). exp2(-cj) folded into fp16 U staging.
__global__ __launch_bounds__(256) void lg_mfma_kernel(
    const float* __restrict__ U, const float* __restrict__ ref,
    float* __restrict__ out, int n) {
  __shared__ float4 sref4[4 * SSTR4];     // 4 bank-skewed copies, 16.4 KB
  __shared__ _Float16 sU[JT * LGL];       // B-fragment-major fp16, 8 KB

  const int t = threadIdx.x;
  const int j0 = blockIdx.y * JT;

  // ---- stage ref: v = 2*s*ref_j, replicated into 4 skewed copies ----
  {
    float4 v = ((const float4*)ref)[j0 + t];
    const float s2 = 2.0f * RSCALE;
    v.x *= s2; v.y *= s2; v.z *= s2; v.w *= s2;
#pragma unroll
    for (int c = 0; c < 4; ++c) sref4[c * SSTR4 + t] = v;
  }
  // ---- stage U -> B-frag-major fp16, scaled by exp2(-cj) ----
  {
    const float4* U4 = (const float4*)U;
    const float4* R4 = (const float4*)ref;
#pragma unroll
    for (int it = 0; it < JT * (LGL / 4) / 256; ++it) {
      const int idx = t + it * 256;
      const int j_rel = idx >> 2;
      const int l0 = (idx & 3) << 2;
      const float4 u = U4[(size_t)(j0 + j_rel) * 4 + (idx & 3)];
      const float4 rv = R4[j0 + j_rel];
      const float cj =
          (rv.x * rv.x + rv.y * rv.y + rv.z * rv.z + rv.w * rv.w) *
          (RSCALE * RSCALE);
      const float f = __builtin_amdgcn_exp2f(-cj);
      const int base = (j_rel >> 5) * 512 + ((j_rel >> 3) & 3) * 128 + (j_rel & 7);
      sU[base + (l0 + 0) * 8] = (_Float16)(u.x * f);
      sU[base + (l0 + 1) * 8] = (_Float16)(u.y * f);
      sU[base + (l0 + 2) * 8] = (_Float16)(u.z * f);
      sU[base + (l0 + 3) * 8] = (_Float16)(u.w * f);
    }
  }
  __syncthreads();

  const int lane = t & 63;
  const int wv = t >> 6;
  const int l = lane & 15;
  const int q = lane >> 4;
  const int ibase = blockIdx.x * 256 + wv * (RT * 16);

  float4 rr[RT];
  float ci[RT];
#pragma unroll
  for (int rt = 0; rt < RT; ++rt) {
    float4 rv = ((const float4*)ref)[ibase + rt * 16 + l];
    rv.x *= RSCALE; rv.y *= RSCALE; rv.z *= RSCALE; rv.w *= RSCALE;
    rr[rt] = rv;
    ci[rt] = rv.x * rv.x + rv.y * rv.y + rv.z * rv.z + rv.w * rv.w;
  }

  f32x4 acc[RT];
#pragma unroll
  for (int rt = 0; rt < RT; ++rt) acc[rt] = (f32x4){0.f, 0.f, 0.f, 0.f};

  const f16x8* sb = (const f16x8*)sU;
  const float4* myref = sref4 + q * SSTR4 + q * 8;  // quad's skewed copy

#pragma unroll 2
  for (int s = 0; s < JT / 32; ++s) {
    float4 b[8];
#pragma unroll
    for (int e = 0; e < 8; ++e) b[e] = myref[s * 32 + e];
    const f16x8 bf = sb[s * 64 + lane];
#pragma unroll
    for (int rt = 0; rt < RT; ++rt) {
      f16x8 af;
#pragma unroll
      for (int e = 0; e < 8; ++e) {
        float a = fmaf(rr[rt].x, b[e].x, -ci[rt]);
        a = fmaf(rr[rt].y, b[e].y, a);
        a = fmaf(rr[rt].z, b[e].z, a);
        a = fmaf(rr[rt].w, b[e].w, a);
        af[e] = (_Float16)__builtin_amdgcn_exp2f(a);
      }
      acc[rt] = __builtin_amdgcn_mfma_f32_16x16x32_f16(af, bf, acc[rt], 0, 0, 0);
    }
  }

  // C/D layout: col = lane&15 (=L channel), row = q*4 + reg (i offset)
#pragma unroll
  for (int rt = 0; rt < RT; ++rt) {
    float* o = out + (size_t)(ibase + rt * 16 + q * 4) * LGL + l;
#pragma unroll
    for (int r = 0; r < 4; ++r) unsafeAtomicAdd(o + r * LGL, acc[rt][r]);
  }
}

extern "C" void kernel_launch(void* const* d_in, const int* in_sizes, int n_in,
                              void* d_out, int out_size, void* d_ws, size_t ws_size,
                              hipStream_t stream) {
  const float* U   = (const float*)d_in[0];
  const float* ref = (const float*)d_in[1];
  float* out = (float*)d_out;

  const int n = in_sizes[1] / LGD;  // 8192

  // out is re-poisoned before every timed call; atomics need zeros
  hipMemsetAsync(d_out, 0, (size_t)out_size * sizeof(float), stream);

  dim3 grid(n / 256, n / JT);  // 32 x 32
  lg_mfma_kernel<<<grid, 256, 0, stream>>>(U, ref, out, n);
}